// Round 3
// baseline (567.927 us; speedup 1.0000x reference)
//
#include <hip/hip_runtime.h>
#include <hip/hip_bf16.h>
#include <cstdint>
#include <cstddef>

#define N_TOK   32768
#define D_IN    1024
#define D_OUT   1024
#define NE      8

#define BM 256
#define BN 256
#define BK 32
#define NTILES (D_IN / BK)   // 32

typedef __attribute__((ext_vector_type(4))) float floatx4;
typedef __attribute__((ext_vector_type(8))) short bf16x8;

__device__ __forceinline__ unsigned short f2bf(float f) {
  union { float f; unsigned int u; } v; v.f = f;
  unsigned int u = v.u + 0x7fffu + ((v.u >> 16) & 1u);   // RNE
  return (unsigned short)(u >> 16);
}

__device__ __forceinline__ unsigned short f2h(float f) {
  union { _Float16 hf; unsigned short us; } c; c.hf = (_Float16)f; return c.us;
}
__device__ __forceinline__ float h2f(unsigned short u) {
  union { _Float16 hf; unsigned short us; } c; c.us = u; return (float)c.hf;
}

// async global->LDS, 16B per lane; LDS dest is wave-uniform base + lane*16
__device__ __forceinline__ void gload_lds16(const void* g, void* l) {
  __builtin_amdgcn_global_load_lds(
      (const __attribute__((address_space(1))) unsigned int*)g,
      (__attribute__((address_space(3))) unsigned int*)l, 16, 0, 0);
}

// ---------------- fused prep: gate (+x cast) | W cast | out zero ----------------
// blocks [0,512): gating, 64 tokens each
// blocks [512,1024): W fp32->bf16, 16 float4/thread
// blocks [1024,3072): zero d_out (atomic mode only; grid is 1024 otherwise)
__global__ __launch_bounds__(256) void prep_kernel(
    const float* __restrict__ x,
    const float* __restrict__ Wg,
    const float* __restrict__ bg,
    const float* __restrict__ W,
    unsigned short* __restrict__ xb,
    unsigned short* __restrict__ Wb,
    int* __restrict__ counts,
    int* __restrict__ bids,
    float* __restrict__ bw,
    int* __restrict__ tok2slot,
    float* __restrict__ out,
    int zero_out)
{
  __shared__ float wg_lds[NE * D_IN];   // 32 KB
  __shared__ int lcnt[NE];
  __shared__ int basee[NE];
  __shared__ int   tok_e[64][2];
  __shared__ int   tok_s[64][2];
  __shared__ float tok_w[64][2];

  const int blk = blockIdx.x;
  const int tid = threadIdx.x;

  if (blk >= 1024) {                 // ---- zero out (atomic mode only) ----
    if (!zero_out) return;
    float4* o4 = (float4*)out;
    const int base = (blk - 1024) * 4096;
#pragma unroll
    for (int i = 0; i < 16; ++i)
      o4[base + i * 256 + tid] = (float4){0.f, 0.f, 0.f, 0.f};
    return;
  }
  if (blk >= 512) {                  // ---- cast W ----
    const float4* s = (const float4*)W;
    const int base = (blk - 512) * 4096;
#pragma unroll
    for (int i = 0; i < 16; ++i) {
      int idx = base + i * 256 + tid;
      float4 v = s[idx];
      ushort4 h;
      h.x = f2bf(v.x); h.y = f2bf(v.y); h.z = f2bf(v.z); h.w = f2bf(v.w);
      ((ushort4*)Wb)[idx] = h;
    }
    return;
  }

  // ---- gating ----
  {
    const float4* s = (const float4*)Wg;
    float4* d = (float4*)wg_lds;
    for (int i = tid; i < NE * D_IN / 4; i += 256) d[i] = s[i];
  }
  if (tid < NE) lcnt[tid] = 0;
  __syncthreads();

  const int wave = tid >> 6, lane = tid & 63;
  const float4* x4 = (const float4*)x;
  const float4* w4 = (const float4*)wg_lds;

  for (int t = 0; t < 16; ++t) {
    const int lt = wave * 16 + t;
    const int n  = blk * 64 + lt;
    float4 xv[4];
    float acc[NE];
#pragma unroll
    for (int e = 0; e < NE; ++e) acc[e] = 0.f;
#pragma unroll
    for (int j = 0; j < 4; ++j) {
      xv[j] = x4[(size_t)n * 256 + j * 64 + lane];
#pragma unroll
      for (int e = 0; e < NE; ++e) {
        float4 w = w4[e * 256 + j * 64 + lane];
        acc[e] += xv[j].x * w.x + xv[j].y * w.y + xv[j].z * w.z + xv[j].w * w.w;
      }
    }
#pragma unroll
    for (int j = 0; j < 4; ++j) {
      ushort4 h;
      h.x = f2bf(xv[j].x); h.y = f2bf(xv[j].y);
      h.z = f2bf(xv[j].z); h.w = f2bf(xv[j].w);
      ((ushort4*)xb)[(size_t)n * 256 + j * 64 + lane] = h;
    }
#pragma unroll
    for (int e = 0; e < NE; ++e)
#pragma unroll
      for (int s = 32; s > 0; s >>= 1)
        acc[e] += __shfl_xor(acc[e], s, 64);

    if (lane == 0) {
      float sc[NE];
#pragma unroll
      for (int e = 0; e < NE; ++e) sc[e] = acc[e] + bg[e];
      float m = sc[0];
#pragma unroll
      for (int e = 1; e < NE; ++e) m = fmaxf(m, sc[e]);
      float p[NE], den = 0.f;
#pragma unroll
      for (int e = 0; e < NE; ++e) { p[e] = __expf(sc[e] - m); den += p[e]; }
      int e1 = 0;
#pragma unroll
      for (int e = 1; e < NE; ++e) if (sc[e] > sc[e1]) e1 = e;   // first-index tie-break
      int e2 = (e1 == 0) ? 1 : 0;
#pragma unroll
      for (int e = 0; e < NE; ++e) if (e != e1 && sc[e] > sc[e2]) e2 = e;
      float inv = 1.f / den;
      tok_e[lt][0] = e1; tok_w[lt][0] = p[e1] * inv; tok_s[lt][0] = atomicAdd(&lcnt[e1], 1);
      tok_e[lt][1] = e2; tok_w[lt][1] = p[e2] * inv; tok_s[lt][1] = atomicAdd(&lcnt[e2], 1);
    }
  }
  __syncthreads();
  if (tid < NE) basee[tid] = atomicAdd(&counts[tid], lcnt[tid]);
  __syncthreads();
  if (tid < 128) {
    int lt = tid >> 1, kk = tid & 1;
    int e = tok_e[lt][kk];
    int slot = basee[e] + tok_s[lt][kk];
    int token = blk * 64 + lt;
    bids[e * N_TOK + slot] = token;
    bw[e * N_TOK + slot]   = tok_w[lt][kk];
    tok2slot[token * 2 + kk] = (e << 15) | slot;    // slot < 32768 always
  }
}

// ---------------- grouped gathered GEMM, 256x256 tile, triple-buffered BK=32 ----------------
// bid = mt*32 + nt*8 + e : e = XCD id (round-robin), expert W stays in its XCD L2.
// 8 waves as 2M x 4N; per-wave 128x64 output. LDS: 3 regions x (A 16KB + B 16KB) = 96KB.
// Pipeline: tile t computes region t%3 while tiles t+1,t+2 stream in; vmcnt(6) per tile
// (never 0 in-loop). LDS chunk-XOR swizzle c^=((row>>1)&3) via pre-swizzled global source.
// mode: 0 = atomicAdd into pre-zeroed out; 1 = fp16 partials to y; 2 = fp32 partials to y
__global__ __launch_bounds__(512, 2) void moe_gemm_kernel(
    const unsigned short* __restrict__ xb,    // [N_TOK, 1024] bf16
    const unsigned short* __restrict__ Wb,    // [8, 1024, 1024] bf16
    const float* __restrict__ bias,           // [8, 1024] fp32
    const int* __restrict__ counts,
    const int* __restrict__ bids,
    const float* __restrict__ bw,
    float* __restrict__ out,
    void* __restrict__ y,
    int mode)
{
  const int bid = blockIdx.x;
  const int e   = bid & 7;
  const int nt  = (bid >> 3) & 3;
  const int mt  = bid >> 5;
  const int cnt = counts[e];
  const int row0 = mt << 8;
  if (row0 >= cnt) return;
  const int rows = min(BM, cnt - row0);

  __shared__ alignas(16) unsigned short Ald[3][BM * BK];  // 3 x 16 KB
  __shared__ alignas(16) unsigned short Bld[3][BN * BK];  // 3 x 16 KB
  __shared__ int   ids[BM];
  __shared__ float wts[BM];

  const int tid = threadIdx.x;
  if (tid < BM) {
    int src = (tid < rows) ? tid : 0;                   // clamp tail rows to a valid id
    ids[tid] = bids[e * N_TOK + row0 + src];
    wts[tid] = (tid < rows) ? bw[e * N_TOK + row0 + tid] : 0.f;
  }
  __syncthreads();

  const int w    = tid >> 6;
  const int lane = tid & 63;
  const int wm   = w >> 2;           // 0..1
  const int wn   = w & 3;            // 0..3
  const int m16  = lane & 15;
  const int quad = lane >> 4;

  const unsigned short* wbe = Wb + (size_t)e * D_OUT * D_IN;

  // staging: group g = w*2+i2 covers 16 rows; lane -> row g*16+(lane>>2), chunk lane&3.
  // source chunk is XOR-swizzled so linear LDS holds the swizzled layout (rule 21).
  size_t a_goff[2], b_goff[2];
  int ldsgrp[2];
#pragma unroll
  for (int i2 = 0; i2 < 2; ++i2) {
    const int g = w * 2 + i2;
    const int r = g * 16 + (lane >> 2);
    const int c = (lane & 3) ^ ((r >> 1) & 3);
    a_goff[i2] = (size_t)ids[r] * D_IN + c * 8;
    b_goff[i2] = (size_t)(nt * BN + r) * D_IN + c * 8;
    ldsgrp[i2] = g * 512;            // elements (16 rows * 32)
  }

  // fragment read offsets (elements); content at swizzled pos (quad ^ f) is chunk quad
  const int swz  = (quad ^ ((m16 >> 1) & 3)) * 8;
  const int roff = m16 * BK + swz;

  floatx4 acc[8][4];
#pragma unroll
  for (int i = 0; i < 8; ++i)
#pragma unroll
    for (int j = 0; j < 4; ++j) acc[i][j] = (floatx4){0.f, 0.f, 0.f, 0.f};

  // prologue: stage tile0 -> region0, tile1 -> region1 (8 loads/wave; FIFO order t0 first)
#pragma unroll
  for (int t0 = 0; t0 < 2; ++t0) {
    const int kb = t0 * BK;
#pragma unroll
    for (int i2 = 0; i2 < 2; ++i2) {
      gload_lds16(xb  + a_goff[i2] + kb, &Ald[t0][ldsgrp[i2]]);
      gload_lds16(wbe + b_goff[i2] + kb, &Bld[t0][ldsgrp[i2]]);
    }
  }

  int rcur = 0, rnxt = 2;
  for (int t = 0; t < NTILES; ++t) {
    const int kb2 = (t + 2 < NTILES ? t + 2 : NTILES - 1) * BK;
    // ---- phase 0: stage A of t+2; wait tile t's 4 (leave 6 in flight); MFMA half 0
    gload_lds16(xb + a_goff[0] + kb2, &Ald[rnxt][ldsgrp[0]]);
    gload_lds16(xb + a_goff[1] + kb2, &Ald[rnxt][ldsgrp[1]]);
    asm volatile("s_waitcnt vmcnt(6)" ::: "memory");
    __builtin_amdgcn_s_barrier();
    asm volatile("" ::: "memory");

    bf16x8 bf[4], af[4];
#pragma unroll
    for (int j = 0; j < 4; ++j)
      bf[j] = *(const bf16x8*)&Bld[rcur][(wn * 64 + j * 16) * BK + roff];
#pragma unroll
    for (int i = 0; i < 4; ++i)
      af[i] = *(const bf16x8*)&Ald[rcur][(wm * 128 + i * 16) * BK + roff];
    __builtin_amdgcn_s_setprio(1);
#pragma unroll
    for (int i = 0; i < 4; ++i)
#pragma unroll
      for (int j = 0; j < 4; ++j)
        acc[i][j] = __builtin_amdgcn_mfma_f32_16x16x32_bf16(af[i], bf[j], acc[i][j], 0, 0, 0);
    __builtin_amdgcn_s_setprio(0);

    // ---- phase 1: stage B of t+2; MFMA half 1; end-of-tile barrier
    gload_lds16(wbe + b_goff[0] + kb2, &Bld[rnxt][ldsgrp[0]]);
    gload_lds16(wbe + b_goff[1] + kb2, &Bld[rnxt][ldsgrp[1]]);
#pragma unroll
    for (int i = 0; i < 4; ++i)
      af[i] = *(const bf16x8*)&Ald[rcur][(wm * 128 + 64 + i * 16) * BK + roff];
    __builtin_amdgcn_s_setprio(1);
#pragma unroll
    for (int i = 0; i < 4; ++i)
#pragma unroll
      for (int j = 0; j < 4; ++j)
        acc[i + 4][j] = __builtin_amdgcn_mfma_f32_16x16x32_bf16(af[i], bf[j], acc[i + 4][j], 0, 0, 0);
    __builtin_amdgcn_s_setprio(0);

    asm volatile("" ::: "memory");
    __builtin_amdgcn_s_barrier();
    asm volatile("" ::: "memory");
    rcur = (rcur == 2) ? 0 : rcur + 1;
    rnxt = (rnxt == 2) ? 0 : rnxt + 1;
  }

  // epilogue: v = w * (acc + bias[col]); C/D map: col=lane&15, row=quad*4+reg
  float bv[4];
  int col[4];
#pragma unroll
  for (int j = 0; j < 4; ++j) {
    col[j] = nt * BN + wn * 64 + j * 16 + m16;
    bv[j] = bias[e * D_OUT + col[j]];
  }

  int ybase = 0;                      // compacted y row base = prefix-sum of counts
  if (mode) {
#pragma unroll
    for (int i = 0; i < NE; ++i) ybase += (i < e) ? counts[i] : 0;
  }

#pragma unroll
  for (int i = 0; i < 8; ++i) {
#pragma unroll
    for (int r = 0; r < 4; ++r) {
      int rl = wm * 128 + i * 16 + quad * 4 + r;
      if (rl < rows) {
        float wgt = wts[rl];
        if (mode == 0) {
          float* orow = out + (size_t)ids[rl] * D_OUT;
#pragma unroll
          for (int j = 0; j < 4; ++j)
            atomicAdd(&orow[col[j]], wgt * (acc[i][j][r] + bv[j]));
        } else if (mode == 2) {
          float* yrow = (float*)y + (size_t)(ybase + row0 + rl) * D_OUT;
#pragma unroll
          for (int j = 0; j < 4; ++j)
            yrow[col[j]] = wgt * (acc[i][j][r] + bv[j]);
        } else {
          unsigned short* yrow = (unsigned short*)y + (size_t)(ybase + row0 + rl) * D_OUT;
#pragma unroll
          for (int j = 0; j < 4; ++j)
            yrow[col[j]] = f2h(wgt * (acc[i][j][r] + bv[j]));
        }
      }
    }
  }
}

// ---------------- combine: out[n] = y[s1(n)] + y[s2(n)] ----------------
__global__ __launch_bounds__(256) void combine_kernel(
    const void* __restrict__ y,
    const int* __restrict__ counts,
    const int* __restrict__ tok2slot,
    float* __restrict__ out,
    int mode)
{
  __shared__ int pre[NE];
  if (threadIdx.x < NE) {
    int s = 0;
    for (int i = 0; i < threadIdx.x; ++i) s += counts[i];
    pre[threadIdx.x] = s;
  }
  __syncthreads();

  const int total = N_TOK * (D_OUT / 4);        // float4 elements of out
  for (int idx = blockIdx.x * 256 + threadIdx.x; idx < total; idx += 2048 * 256) {
    int row = idx >> 8, c4 = idx & 255;
    int v1 = tok2slot[row * 2], v2 = tok2slot[row * 2 + 1];
    long r1 = pre[v1 >> 15] + (v1 & 32767);
    long r2 = pre[v2 >> 15] + (v2 & 32767);
    float4 o;
    if (mode == 2) {
      const float4* y4 = (const float4*)y;
      float4 a = y4[r1 * 256 + c4];
      float4 b = y4[r2 * 256 + c4];
      o.x = a.x + b.x; o.y = a.y + b.y; o.z = a.z + b.z; o.w = a.w + b.w;
    } else {
      const ushort4* y4 = (const ushort4*)y;
      ushort4 a = y4[r1 * 256 + c4];
      ushort4 b = y4[r2 * 256 + c4];
      o.x = h2f(a.x) + h2f(b.x); o.y = h2f(a.y) + h2f(b.y);
      o.z = h2f(a.z) + h2f(b.z); o.w = h2f(a.w) + h2f(b.w);
    }
    ((float4*)out)[idx] = o;
  }
}

extern "C" void kernel_launch(void* const* d_in, const int* in_sizes, int n_in,
                              void* d_out, int out_size, void* d_ws, size_t ws_size,
                              hipStream_t stream) {
  const float* x  = (const float*)d_in[0];
  const float* Wg = (const float*)d_in[1];
  const float* bg = (const float*)d_in[2];
  const float* W  = (const float*)d_in[3];
  const float* b  = (const float*)d_in[4];
  float* out = (float*)d_out;

  // workspace layout:
  // counts(4KB) | bids(1MB) | bw(1MB) | tok2slot(256KB) | xb(64MB) | Wb(16MB) | y(0/128/256MB)
  char* ws = (char*)d_ws;
  size_t off = 0;
  int*   counts   = (int*)(ws + off);  off += 4096;
  int*   bids     = (int*)(ws + off);  off += (size_t)NE * N_TOK * 4;
  float* bw       = (float*)(ws + off); off += (size_t)NE * N_TOK * 4;
  int*   tok2slot = (int*)(ws + off);  off += (size_t)N_TOK * 2 * 4;
  unsigned short* xb = (unsigned short*)(ws + off); off += (size_t)N_TOK * D_IN * 2;
  unsigned short* Wb = (unsigned short*)(ws + off); off += (size_t)NE * D_IN * D_OUT * 2;
  void* y = (void*)(ws + off);
  const size_t y_rows = 2 * (size_t)N_TOK;           // exactly sum(counts) = 65536
  const size_t need_f32 = off + y_rows * D_OUT * 4;
  const size_t need_f16 = off + y_rows * D_OUT * 2;

  int mode = (ws_size >= need_f32) ? 2 : (ws_size >= need_f16 ? 1 : 0);

  hipMemsetAsync(counts, 0, NE * sizeof(int), stream);
  prep_kernel<<<mode == 0 ? 3072 : 1024, 256, 0, stream>>>(
      x, Wg, bg, W, xb, Wb, counts, bids, bw, tok2slot, out, mode == 0 ? 1 : 0);
  moe_gemm_kernel<<<NE * 4 * (N_TOK / BM), 512, 0, stream>>>(
      xb, Wb, b, counts, bids, bw, out, y, mode);
  if (mode != 0)
    combine_kernel<<<2048, 256, 0, stream>>>(y, counts, tok2slot, out, mode);
}

// Round 4
// 511.017 us; speedup vs baseline: 1.1114x; 1.1114x over previous
//
#include <hip/hip_runtime.h>
#include <hip/hip_bf16.h>
#include <cstdint>
#include <cstddef>

#define N_TOK   32768
#define D_IN    1024
#define D_OUT   1024
#define NE      8

#define BM 128
#define BN 128
#define BK 64
#define NKT (D_IN / BK)   // 16

typedef __attribute__((ext_vector_type(4))) float floatx4;
typedef __attribute__((ext_vector_type(8))) short bf16x8;

__device__ __forceinline__ unsigned short f2bf(float f) {
  union { float f; unsigned int u; } v; v.f = f;
  unsigned int u = v.u + 0x7fffu + ((v.u >> 16) & 1u);   // RNE
  return (unsigned short)(u >> 16);
}

__device__ __forceinline__ unsigned short f2h(float f) {
  union { _Float16 hf; unsigned short us; } c; c.hf = (_Float16)f; return c.us;
}
__device__ __forceinline__ float h2f(unsigned short u) {
  union { _Float16 hf; unsigned short us; } c; c.us = u; return (float)c.hf;
}

// async global->LDS, 16B per lane; LDS dest is wave-uniform base + lane*16
__device__ __forceinline__ void gload_lds16(const void* g, void* l) {
  __builtin_amdgcn_global_load_lds(
      (const __attribute__((address_space(1))) unsigned int*)g,
      (__attribute__((address_space(3))) unsigned int*)l, 16, 0, 0);
}

// ---------------- fused prep: gate (+x cast) | W cast ----------------
// blocks [0,512): gating, 64 tokens each
// blocks [512,1024): W fp32->bf16, 16 float4/thread
// blocks [1024,3072): zero d_out (atomic fallback mode only)
__global__ __launch_bounds__(256) void prep_kernel(
    const float* __restrict__ x,
    const float* __restrict__ Wg,
    const float* __restrict__ bg,
    const float* __restrict__ W,
    unsigned short* __restrict__ xb,
    unsigned short* __restrict__ Wb,
    int* __restrict__ counts,
    int* __restrict__ bids,
    float* __restrict__ bw,
    int* __restrict__ tok2slot,
    float* __restrict__ out,
    int zero_out)
{
  __shared__ float wg_lds[NE * D_IN];   // 32 KB
  __shared__ int lcnt[NE];
  __shared__ int basee[NE];
  __shared__ int   tok_e[64][2];
  __shared__ int   tok_s[64][2];
  __shared__ float tok_w[64][2];

  const int blk = blockIdx.x;
  const int tid = threadIdx.x;

  if (blk >= 1024) {                 // ---- zero out (atomic mode only) ----
    if (!zero_out) return;
    float4* o4 = (float4*)out;
    const int base = (blk - 1024) * 4096;
#pragma unroll
    for (int i = 0; i < 16; ++i)
      o4[base + i * 256 + tid] = (float4){0.f, 0.f, 0.f, 0.f};
    return;
  }
  if (blk >= 512) {                  // ---- cast W ----
    const float4* s = (const float4*)W;
    const int base = (blk - 512) * 4096;
#pragma unroll
    for (int i = 0; i < 16; ++i) {
      int idx = base + i * 256 + tid;
      float4 v = s[idx];
      ushort4 h;
      h.x = f2bf(v.x); h.y = f2bf(v.y); h.z = f2bf(v.z); h.w = f2bf(v.w);
      ((ushort4*)Wb)[idx] = h;
    }
    return;
  }

  // ---- gating ----
  {
    const float4* s = (const float4*)Wg;
    float4* d = (float4*)wg_lds;
    for (int i = tid; i < NE * D_IN / 4; i += 256) d[i] = s[i];
  }
  if (tid < NE) lcnt[tid] = 0;
  __syncthreads();

  const int wave = tid >> 6, lane = tid & 63;
  const float4* x4 = (const float4*)x;
  const float4* w4 = (const float4*)wg_lds;

  for (int t = 0; t < 16; ++t) {
    const int lt = wave * 16 + t;
    const int n  = blk * 64 + lt;
    float4 xv[4];
    float acc[NE];
#pragma unroll
    for (int e = 0; e < NE; ++e) acc[e] = 0.f;
#pragma unroll
    for (int j = 0; j < 4; ++j) {
      xv[j] = x4[(size_t)n * 256 + j * 64 + lane];
#pragma unroll
      for (int e = 0; e < NE; ++e) {
        float4 w = w4[e * 256 + j * 64 + lane];
        acc[e] += xv[j].x * w.x + xv[j].y * w.y + xv[j].z * w.z + xv[j].w * w.w;
      }
    }
#pragma unroll
    for (int j = 0; j < 4; ++j) {
      ushort4 h;
      h.x = f2bf(xv[j].x); h.y = f2bf(xv[j].y);
      h.z = f2bf(xv[j].z); h.w = f2bf(xv[j].w);
      ((ushort4*)xb)[(size_t)n * 256 + j * 64 + lane] = h;
    }
#pragma unroll
    for (int e = 0; e < NE; ++e)
#pragma unroll
      for (int s = 32; s > 0; s >>= 1)
        acc[e] += __shfl_xor(acc[e], s, 64);

    if (lane == 0) {
      float sc[NE];
#pragma unroll
      for (int e = 0; e < NE; ++e) sc[e] = acc[e] + bg[e];
      float m = sc[0];
#pragma unroll
      for (int e = 1; e < NE; ++e) m = fmaxf(m, sc[e]);
      float p[NE], den = 0.f;
#pragma unroll
      for (int e = 0; e < NE; ++e) { p[e] = __expf(sc[e] - m); den += p[e]; }
      int e1 = 0;
#pragma unroll
      for (int e = 1; e < NE; ++e) if (sc[e] > sc[e1]) e1 = e;   // first-index tie-break
      int e2 = (e1 == 0) ? 1 : 0;
#pragma unroll
      for (int e = 0; e < NE; ++e) if (e != e1 && sc[e] > sc[e2]) e2 = e;
      float inv = 1.f / den;
      tok_e[lt][0] = e1; tok_w[lt][0] = p[e1] * inv; tok_s[lt][0] = atomicAdd(&lcnt[e1], 1);
      tok_e[lt][1] = e2; tok_w[lt][1] = p[e2] * inv; tok_s[lt][1] = atomicAdd(&lcnt[e2], 1);
    }
  }
  __syncthreads();
  if (tid < NE) basee[tid] = atomicAdd(&counts[tid], lcnt[tid]);
  __syncthreads();
  if (tid < 128) {
    int lt = tid >> 1, kk = tid & 1;
    int e = tok_e[lt][kk];
    int slot = basee[e] + tok_s[lt][kk];
    int token = blk * 64 + lt;
    bids[e * N_TOK + slot] = token;
    bw[e * N_TOK + slot]   = tok_w[lt][kk];
    tok2slot[token * 2 + kk] = (e << 15) | slot;    // slot < 32768 always
  }
}

// ---------------- grouped gathered GEMM: m97 structure ----------------
// 128x128 tile, BK=64, single 33KB LDS buffer, 4 waves (2x2), full vmcnt(0) drain per
// tile; latency hidden by ~3 co-resident blocks/CU (m97's mechanism, 874 TF dense).
// XOR swizzle chunk^= (row&7) on 16B chunks of the 128B rows: staging fetches the
// inverse-permuted global chunk into linear LDS; reads apply the same XOR (rule 21).
// bid = mt*64 + nt*8 + e : e = XCD id, expert W stays in its XCD L2.
// mode: 0 = atomicAdd into pre-zeroed out; 1 = fp16 partials to y; 2 = fp32 partials
__global__ __launch_bounds__(256, 3) void moe_gemm_kernel(
    const unsigned short* __restrict__ xb,    // [N_TOK, 1024] bf16
    const unsigned short* __restrict__ Wb,    // [8, 1024, 1024] bf16
    const float* __restrict__ bias,           // [8, 1024] fp32
    const int* __restrict__ counts,
    const int* __restrict__ bids,
    const float* __restrict__ bw,
    float* __restrict__ out,
    void* __restrict__ y,
    int mode)
{
  const int bid = blockIdx.x;
  const int e   = bid & 7;
  const int nt  = (bid >> 3) & 7;
  const int mt  = bid >> 6;
  const int cnt = counts[e];
  const int row0 = mt << 7;
  if (row0 >= cnt) return;
  const int rows = min(BM, cnt - row0);

  __shared__ alignas(16) unsigned short Ald[BM * BK];   // 16 KB
  __shared__ alignas(16) unsigned short Bld[BN * BK];   // 16 KB
  __shared__ int   ids[BM];
  __shared__ float wts[BM];

  const int tid = threadIdx.x;
  if (tid < BM) {
    int src = (tid < rows) ? tid : 0;                   // clamp tail rows to a valid id
    ids[tid] = bids[e * N_TOK + row0 + src];
    wts[tid] = (tid < rows) ? bw[e * N_TOK + row0 + tid] : 0.f;
  }
  __syncthreads();

  const int w    = tid >> 6;
  const int lane = tid & 63;
  const int wm   = w >> 1, wn = w & 1;
  const int m16  = lane & 15;
  const int quad = lane >> 4;

  const unsigned short* wbe = Wb + (size_t)e * D_OUT * D_IN;

  // staging: 1024 16B-chunks per matrix; thread covers chunks q = l*256+tid, l=0..3.
  // chunk q -> row r=q>>3, LDS slot s=q&7; fetch logical chunk c = s ^ (r&7) so the
  // linear LDS holds the swizzled layout.
  int a_off[4], b_off[4];           // element offsets (fit in int: < 2^25)
  int lds_off[4];                   // wave-uniform LDS element base per l
#pragma unroll
  for (int l = 0; l < 4; ++l) {
    const int q = l * 256 + tid;
    const int r = q >> 3;
    const int c = (q & 7) ^ (r & 7);
    a_off[l] = ids[r] * D_IN + c * 8;
    b_off[l] = (nt * BN + r) * D_IN + c * 8;
    lds_off[l] = (l * 256 + w * 64) * 8;   // + lane*8 applied by hardware (16B/lane)
  }

  floatx4 acc[4][4];
#pragma unroll
  for (int i = 0; i < 4; ++i)
#pragma unroll
    for (int j = 0; j < 4; ++j) acc[i][j] = (floatx4){0.f, 0.f, 0.f, 0.f};

  for (int kt = 0; kt < NKT; ++kt) {
    const int kb = kt * BK;
#pragma unroll
    for (int l = 0; l < 4; ++l)
      gload_lds16(xb + a_off[l] + kb, &Ald[lds_off[l]]);
#pragma unroll
    for (int l = 0; l < 4; ++l)
      gload_lds16(wbe + b_off[l] + kb, &Bld[lds_off[l]]);

    asm volatile("s_waitcnt vmcnt(0)" ::: "memory");
    __builtin_amdgcn_s_barrier();
    asm volatile("" ::: "memory");

#pragma unroll
    for (int ks = 0; ks < 2; ++ks) {
      const int sw = (((ks << 2) | quad) ^ (m16 & 7)) * 8;
      bf16x8 af[4], bf[4];
#pragma unroll
      for (int j = 0; j < 4; ++j)
        bf[j] = *(const bf16x8*)&Bld[(wn * 64 + j * 16 + m16) * BK + sw];
#pragma unroll
      for (int i = 0; i < 4; ++i)
        af[i] = *(const bf16x8*)&Ald[(wm * 64 + i * 16 + m16) * BK + sw];
      __builtin_amdgcn_s_setprio(1);
#pragma unroll
      for (int i = 0; i < 4; ++i)
#pragma unroll
        for (int j = 0; j < 4; ++j)
          acc[i][j] = __builtin_amdgcn_mfma_f32_16x16x32_bf16(af[i], bf[j], acc[i][j], 0, 0, 0);
      __builtin_amdgcn_s_setprio(0);
    }

    asm volatile("" ::: "memory");
    __builtin_amdgcn_s_barrier();
    asm volatile("" ::: "memory");
  }

  // epilogue: v = w * (acc + bias[col]); C/D map: col=lane&15, row=quad*4+reg
  float bv[4];
  int col[4];
#pragma unroll
  for (int j = 0; j < 4; ++j) {
    col[j] = nt * BN + wn * 64 + j * 16 + m16;
    bv[j] = bias[e * D_OUT + col[j]];
  }

  int ybase = 0;                      // compacted y row base = prefix-sum of counts
  if (mode) {
#pragma unroll
    for (int i = 0; i < NE; ++i) ybase += (i < e) ? counts[i] : 0;
  }

#pragma unroll
  for (int i = 0; i < 4; ++i) {
#pragma unroll
    for (int r = 0; r < 4; ++r) {
      int rl = wm * 64 + i * 16 + quad * 4 + r;
      if (rl < rows) {
        float wgt = wts[rl];
        if (mode == 0) {
          float* orow = out + (size_t)ids[rl] * D_OUT;
#pragma unroll
          for (int j = 0; j < 4; ++j)
            atomicAdd(&orow[col[j]], wgt * (acc[i][j][r] + bv[j]));
        } else if (mode == 2) {
          float* yrow = (float*)y + (size_t)(ybase + row0 + rl) * D_OUT;
#pragma unroll
          for (int j = 0; j < 4; ++j)
            yrow[col[j]] = wgt * (acc[i][j][r] + bv[j]);
        } else {
          unsigned short* yrow = (unsigned short*)y + (size_t)(ybase + row0 + rl) * D_OUT;
#pragma unroll
          for (int j = 0; j < 4; ++j)
            yrow[col[j]] = f2h(wgt * (acc[i][j][r] + bv[j]));
        }
      }
    }
  }
}

// ---------------- combine: out[n] = y[s1(n)] + y[s2(n)] ----------------
__global__ __launch_bounds__(256) void combine_kernel(
    const void* __restrict__ y,
    const int* __restrict__ counts,
    const int* __restrict__ tok2slot,
    float* __restrict__ out,
    int mode)
{
  __shared__ int pre[NE];
  if (threadIdx.x < NE) {
    int s = 0;
    for (int i = 0; i < threadIdx.x; ++i) s += counts[i];
    pre[threadIdx.x] = s;
  }
  __syncthreads();

  const int total = N_TOK * (D_OUT / 4);        // float4 elements of out
  for (int idx = blockIdx.x * 256 + threadIdx.x; idx < total; idx += 2048 * 256) {
    int row = idx >> 8, c4 = idx & 255;
    int v1 = tok2slot[row * 2], v2 = tok2slot[row * 2 + 1];
    long r1 = pre[v1 >> 15] + (v1 & 32767);
    long r2 = pre[v2 >> 15] + (v2 & 32767);
    float4 o;
    if (mode == 2) {
      const float4* y4 = (const float4*)y;
      float4 a = y4[r1 * 256 + c4];
      float4 b = y4[r2 * 256 + c4];
      o.x = a.x + b.x; o.y = a.y + b.y; o.z = a.z + b.z; o.w = a.w + b.w;
    } else {
      const ushort4* y4 = (const ushort4*)y;
      ushort4 a = y4[r1 * 256 + c4];
      ushort4 b = y4[r2 * 256 + c4];
      o.x = h2f(a.x) + h2f(b.x); o.y = h2f(a.y) + h2f(b.y);
      o.z = h2f(a.z) + h2f(b.z); o.w = h2f(a.w) + h2f(b.w);
    }
    ((float4*)out)[idx] = o;
  }
}

extern "C" void kernel_launch(void* const* d_in, const int* in_sizes, int n_in,
                              void* d_out, int out_size, void* d_ws, size_t ws_size,
                              hipStream_t stream) {
  const float* x  = (const float*)d_in[0];
  const float* Wg = (const float*)d_in[1];
  const float* bg = (const float*)d_in[2];
  const float* W  = (const float*)d_in[3];
  const float* b  = (const float*)d_in[4];
  float* out = (float*)d_out;

  // workspace layout:
  // counts(4KB) | bids(1MB) | bw(1MB) | tok2slot(256KB) | xb(64MB) | Wb(16MB) | y(0/128/256MB)
  char* ws = (char*)d_ws;
  size_t off = 0;
  int*   counts   = (int*)(ws + off);  off += 4096;
  int*   bids     = (int*)(ws + off);  off += (size_t)NE * N_TOK * 4;
  float* bw       = (float*)(ws + off); off += (size_t)NE * N_TOK * 4;
  int*   tok2slot = (int*)(ws + off);  off += (size_t)N_TOK * 2 * 4;
  unsigned short* xb = (unsigned short*)(ws + off); off += (size_t)N_TOK * D_IN * 2;
  unsigned short* Wb = (unsigned short*)(ws + off); off += (size_t)NE * D_IN * D_OUT * 2;
  void* y = (void*)(ws + off);
  const size_t y_rows = 2 * (size_t)N_TOK;           // exactly sum(counts) = 65536
  const size_t need_f32 = off + y_rows * D_OUT * 4;
  const size_t need_f16 = off + y_rows * D_OUT * 2;

  int mode = (ws_size >= need_f32) ? 2 : (ws_size >= need_f16 ? 1 : 0);

  hipMemsetAsync(counts, 0, NE * sizeof(int), stream);
  prep_kernel<<<mode == 0 ? 3072 : 1024, 256, 0, stream>>>(
      x, Wg, bg, W, xb, Wb, counts, bids, bw, tok2slot, out, mode == 0 ? 1 : 0);
  moe_gemm_kernel<<<NE * 8 * (N_TOK / BM), 256, 0, stream>>>(
      xb, Wb, b, counts, bids, bw, out, y, mode);
  if (mode != 0)
    combine_kernel<<<2048, 256, 0, stream>>>(y, counts, tok2slot, out, mode);
}